// Round 5
// baseline (111.443 us; speedup 1.0000x reference)
//
#include <hip/hip_runtime.h>
#include <hip/hip_bf16.h>
#include <cstdint>

#define Bc 2
#define Nc 3072
#define Hc 4
#define NW32 96      // 32-key tiles per row

typedef __bf16 bf16x8 __attribute__((ext_vector_type(8)));
typedef float  f32x4  __attribute__((ext_vector_type(4)));
typedef float  f32x16 __attribute__((ext_vector_type(16)));

#define QSCALE 0.18033688f   // 0.125 * log2(e): exp(s/8) == exp2(s*QSCALE)

static __device__ __forceinline__ f32x16 mfma32(bf16x8 a, bf16x8 b, f32x16 c) {
    return __builtin_amdgcn_mfma_f32_32x32x16_bf16(a, b, c, 0, 0, 0);
}
static __device__ __forceinline__ void gload_lds16(const void* g, void* l) {
    __builtin_amdgcn_global_load_lds((const __attribute__((address_space(1))) void*)g,
                                     (__attribute__((address_space(3))) void*)l, 16, 0, 0);
}

// ---- W prep: [h][d][o] f32 -> Wb[p][h][o][d] bf16 hi/lo; Q pre-scaled by QSCALE ----
__global__ void wb_kernel(const float* __restrict__ Wq, const float* __restrict__ Wk,
                          const float* __restrict__ Wv,
                          const float* __restrict__ bq, const float* __restrict__ bk,
                          const float* __restrict__ bv,
                          __bf16* __restrict__ Wbh, __bf16* __restrict__ Wbl,
                          float* __restrict__ Bs)
{
    int i = blockIdx.x*256 + threadIdx.x;   // 49152
    int d = i & 63, o = (i >> 6) & 63, h = (i >> 12) & 3, p = i >> 14;
    const float* W = (p == 0) ? Wq : (p == 1) ? Wk : Wv;
    float scale = (p == 0) ? QSCALE : 1.0f;
    float val = W[(h*64 + d)*64 + o] * scale;
    int idx = (((p*Hc + h)*64 + o) << 6) + d;
    __bf16 hi = (__bf16)val;
    Wbh[idx] = hi;
    Wbl[idx] = (__bf16)(val - (float)hi);
    if (i < 3*Hc*64) {   // bias, pre-scaled: Bs[p][h][o]
        int pp = i / (Hc*64), rest = i % (Hc*64);
        const float* B = (pp == 0) ? bq : (pp == 1) ? bk : bv;
        Bs[i] = B[rest] * ((pp == 0) ? QSCALE : 1.0f);
    }
}

// ---- x pre-split: f32 [b][n][64] -> bf16 hi/lo planes ----
__global__ void xsplit_kernel(const float* __restrict__ x,
                              __bf16* __restrict__ Xh, __bf16* __restrict__ Xl)
{
    int i = blockIdx.x*256 + threadIdx.x;   // 49152 threads x 8 elems
    const float4* xp = (const float4*)(x + (size_t)i*8);
    float4 a = xp[0], c = xp[1];
    float v[8] = {a.x, a.y, a.z, a.w, c.x, c.y, c.z, c.w};
    bf16x8 h, l;
    #pragma unroll
    for (int j = 0; j < 8; ++j) {
        __bf16 hh = (__bf16)v[j];
        h[j] = hh;
        l[j] = (__bf16)(v[j] - (float)hh);
    }
    *(bf16x8*)(Xh + (size_t)i*8) = h;
    *(bf16x8*)(Xl + (size_t)i*8) = l;
}

// ---- QKV projection via MFMA: planes [bh][n][64] bf16 hi/lo ----
__global__ __launch_bounds__(256) void qkv_mfma(
    const __bf16* __restrict__ Xh, const __bf16* __restrict__ Xl,
    const __bf16* __restrict__ Wbh, const __bf16* __restrict__ Wbl,
    const float* __restrict__ Bs,
    __bf16* __restrict__ Qh, __bf16* __restrict__ Ql,
    __bf16* __restrict__ Kh, __bf16* __restrict__ Kl,
    __bf16* __restrict__ Vh0, __bf16* __restrict__ Vl0)
{
    const int lane = threadIdx.x & 63, w = threadIdx.x >> 6;
    const int l31 = lane & 31, hi = lane >> 5;
    int t = blockIdx.x;                 // 1152 blocks
    int nt = t % 48; t /= 48;
    int b  = t & 1;  t >>= 1;
    int p  = t % 3;
    int h  = t / 3;
    const int r0 = (w >> 1)*32, c0 = (w & 1)*32, n0 = nt*64;

    bf16x8 xh[4], xl[4], wh[4], wl[4];
    #pragma unroll
    for (int kk = 0; kk < 4; ++kk) {
        size_t xoff = (((size_t)(b*Nc + n0 + r0 + l31)) << 6) + kk*16 + hi*8;
        xh[kk] = *(const bf16x8*)(Xh + xoff);
        xl[kk] = *(const bf16x8*)(Xl + xoff);
        size_t woff = (((size_t)((p*Hc + h)*64 + c0 + l31)) << 6) + kk*16 + hi*8;
        wh[kk] = *(const bf16x8*)(Wbh + woff);
        wl[kk] = *(const bf16x8*)(Wbl + woff);
    }
    float bias = Bs[(p*Hc + h)*64 + c0 + l31];
    f32x16 acc;
    #pragma unroll
    for (int i = 0; i < 16; ++i) acc[i] = bias;
    #pragma unroll
    for (int kk = 0; kk < 4; ++kk) {
        acc = mfma32(xh[kk], wh[kk], acc);
        acc = mfma32(xl[kk], wh[kk], acc);
        acc = mfma32(xh[kk], wl[kk], acc);
    }
    __bf16* dh = (p == 0) ? Qh : (p == 1) ? Kh : Vh0;
    __bf16* dl = (p == 0) ? Ql : (p == 1) ? Kl : Vl0;
    const int bh = b*Hc + h;
    #pragma unroll
    for (int r = 0; r < 16; ++r) {
        int row = (r & 3) + 8*(r >> 2) + 4*hi;
        size_t idx = (((size_t)bh*Nc + n0 + r0 + row) << 6) + c0 + l31;
        float val = acc[r];
        __bf16 hh = (__bf16)val;
        dh[idx] = hh;
        dl[idx] = (__bf16)(val - (float)hh);
    }
}

// ---- build per-tile 16KB LDS images: KVimg[bh][t] = {Kh|Kl|Vh|Vl} granules ----
__global__ __launch_bounds__(256) void img_kernel(
    const __bf16* __restrict__ Kh, const __bf16* __restrict__ Kl,
    const __bf16* __restrict__ Vh0, const __bf16* __restrict__ Vl0,
    __bf16* __restrict__ KVimg)
{
    __shared__ __bf16 tile[32][64];
    const int tid = threadIdx.x;
    const int t = blockIdx.x % 96, bh = blockIdx.x / 96;
    char* img = (char*)KVimg + (((size_t)bh*96 + t) << 14);
    {
        int key = tid & 31, dc = tid >> 5;
        size_t src = (((size_t)bh*Nc + t*32 + key) << 6) + dc*8;
        *(bf16x8*)(img + (dc*32 + key)*16)        = *(const bf16x8*)(Kh + src);
        *(bf16x8*)(img + 4096 + (dc*32 + key)*16) = *(const bf16x8*)(Kl + src);
    }
    #pragma unroll
    for (int pl = 0; pl < 2; ++pl) {
        const __bf16* vp = pl ? Vl0 : Vh0;
        __syncthreads();
        {
            int n2 = tid >> 3, seg = (tid & 7)*8;
            *(bf16x8*)&tile[n2][seg] =
                *(const bf16x8*)(vp + (((size_t)bh*Nc + t*32 + n2) << 6) + seg);
        }
        __syncthreads();
        int o = tid & 63, kb = tid >> 6;
        __bf16 g[8];
        #pragma unroll
        for (int j = 0; j < 8; ++j) g[j] = tile[kb*8 + j][o];
        *(bf16x8*)(img + 8192 + pl*4096 + (kb*64 + o)*16) = *(bf16x8*)g;
    }
}

// ---- pack adjacency transposed: pmT[b][w][n], bit j = edge[b][n][32w+j] ----
__global__ void pack_kernel(const int* __restrict__ edge, uint32_t* __restrict__ pmT)
{
    int gw = blockIdx.x*4 + (threadIdx.x >> 6);
    int lane = threadIdx.x & 63;
    int ng = gw % 48; gw /= 48;
    int w  = gw % NW32; gw /= NW32;
    int b  = gw;
    int n = ng*64 + lane;
    const uint4* ep = (const uint4*)(edge + ((size_t)b*Nc + n)*Nc + w*32);
    uint32_t word = 0;
    #pragma unroll
    for (int i = 0; i < 8; ++i) {
        uint4 e = ep[i];
        word |= (e.x ? 1u : 0u) << (4*i);
        word |= (e.y ? 1u : 0u) << (4*i + 1);
        word |= (e.z ? 1u : 0u) << (4*i + 2);
        word |= (e.w ? 1u : 0u) << (4*i + 3);
    }
    pmT[((size_t)b*NW32 + w)*Nc + n] = word;
}

// ---- flash attention: counted-vmcnt 2-buffer pipeline, in-register softmax ----
__global__ __launch_bounds__(256, 4) void attn_mfma(
    const __bf16* __restrict__ Qh, const __bf16* __restrict__ Ql,
    const __bf16* __restrict__ KVimg, const uint32_t* __restrict__ pmT,
    float* __restrict__ PA, float* __restrict__ PL, int KS, int tps)
{
    __shared__ __align__(16) char ldsKV[2][16384];
    const int lane = threadIdx.x & 63, w = threadIdx.x >> 6;
    const int l31 = lane & 31, hi = lane >> 5;
    int gb = blockIdx.x;
    const int bh = gb & 7; gb >>= 3;        // XCD swizzle: one bh per XCD
    const int qt = gb % 24;
    const int ks = gb / 24;
    const int b = bh >> 2;
    const int qrow0 = qt*128 + w*32;

    // Q B-fragments (col = q-row = l31, k = d), pre-scaled by QSCALE
    bf16x8 qh[4], ql[4];
    #pragma unroll
    for (int kk = 0; kk < 4; ++kk) {
        size_t qoff = (((size_t)bh*Nc + qrow0 + l31) << 6) + kk*16 + hi*8;
        qh[kk] = *(const bf16x8*)(Qh + qoff);
        ql[kk] = *(const bf16x8*)(Ql + qoff);
    }

    f32x16 acc0, acc1;
    #pragma unroll
    for (int i = 0; i < 16; ++i) { acc0[i] = 0.f; acc1[i] = 0.f; }
    float lsum = 0.f;

    const char* img = (const char*)KVimg + (((size_t)bh*96) << 14);
    const int t0 = ks*tps;

    // prologue stage into buf0 (wave w covers bytes [w*4096, (w+1)*4096))
    #pragma unroll
    for (int g = 0; g < 4; ++g)
        gload_lds16(img + (((size_t)t0) << 14) + w*4096 + g*1024 + lane*16,
                    &ldsKV[0][w*4096 + g*1024]);

    int cur = 0;
    #pragma unroll 1
    for (int it = 0; it < tps; ++it) {
        const int t = t0 + it;
        if (it + 1 < tps) {
            #pragma unroll
            for (int g = 0; g < 4; ++g)
                gload_lds16(img + (((size_t)(t + 1)) << 14) + w*4096 + g*1024 + lane*16,
                            &ldsKV[cur ^ 1][w*4096 + g*1024]);
        }
        // counted wait: allow next tile's 4 loads to stay in flight
        asm volatile("s_waitcnt vmcnt(4)" ::: "memory");
        __builtin_amdgcn_s_barrier();
        asm volatile("" ::: "memory");
        const char* Lb = &ldsKV[cur][0];

        // ---- QK^T: single accumulator chain, 12 MFMA ----
        f32x16 sc;
        #pragma unroll
        for (int i = 0; i < 16; ++i) sc[i] = 0.f;
        #pragma unroll
        for (int kk = 0; kk < 4; ++kk) {
            bf16x8 ka = *(const bf16x8*)(Lb + ((kk*2 + hi) << 9) + (l31 << 4));
            bf16x8 la = *(const bf16x8*)(Lb + 4096 + ((kk*2 + hi) << 9) + (l31 << 4));
            sc = mfma32(ka, qh[kk], sc);
            sc = mfma32(la, qh[kk], sc);
            sc = mfma32(ka, ql[kk], sc);
        }
        // scores: lane owns q=l31; reg r -> key (r&3)+8(r>>2)+4hi; scaled by log2e/8

        // ---- in-register softmax (exp2, masked) -> packed bf16 pairs ----
        uint32_t mw  = pmT[((size_t)b*NW32 + t)*Nc + qrow0 + l31];
        uint32_t mwh = mw >> (hi*4);
        uint32_t W8[8];
        #pragma unroll
        for (int i = 0; i < 8; ++i) {
            const int r0 = 2*i, r1 = 2*i + 1;
            const int bp0 = (r0 & 3) + 8*(r0 >> 2);
            const int bp1 = (r1 & 3) + 8*(r1 >> 2);
            float s0 = sc[2*i], s1 = sc[2*i + 1];
            float a0 = fmaxf(s0, 0.2f*s0);       // leaky (commutes with +scale)
            float a1 = fmaxf(s1, 0.2f*s1);
            float e0, e1;
            asm("v_exp_f32 %0, %1" : "=v"(e0) : "v"(a0));   // exp2
            asm("v_exp_f32 %0, %1" : "=v"(e1) : "v"(a1));
            uint32_t m0 = (uint32_t)(((int)(mwh << (31 - bp0))) >> 31);
            uint32_t m1 = (uint32_t)(((int)(mwh << (31 - bp1))) >> 31);
            float p0 = __uint_as_float(__float_as_uint(e0) & m0);
            float p1 = __uint_as_float(__float_as_uint(e1) & m1);
            lsum += p0 + p1;                      // denom mismatch vs bf16 p: ~2.5e-5 rel
            uint32_t wv;
            asm("v_cvt_pk_bf16_f32 %0, %1, %2" : "=v"(wv) : "v"(p0), "v"(p1));
            W8[i] = wv;
        }
        // ---- permlane assembly of PV A-frags ----
        uint32_t a0 = W8[0], a2 = W8[2], a1 = W8[1], a3 = W8[3];
        uint32_t b0 = W8[4], b2 = W8[6], b1 = W8[5], b3 = W8[7];
        asm("v_permlane32_swap_b32 %0, %1" : "+v"(a0), "+v"(a2));
        asm("v_permlane32_swap_b32 %0, %1" : "+v"(a1), "+v"(a3));
        asm("v_permlane32_swap_b32 %0, %1" : "+v"(b0), "+v"(b2));
        asm("v_permlane32_swap_b32 %0, %1" : "+v"(b1), "+v"(b3));
        union { uint32_t u[4]; bf16x8 v; } pa0, pa1;
        pa0.u[0] = a0; pa0.u[1] = a1; pa0.u[2] = a2; pa0.u[3] = a3;
        pa1.u[0] = b0; pa1.u[1] = b1; pa1.u[2] = b2; pa1.u[3] = b3;

        // ---- PV (A = P regs, B = V from LDS) ----
        #pragma unroll
        for (int kkp = 0; kkp < 2; ++kkp) {
            bf16x8 pa = kkp ? pa1.v : pa0.v;
            #pragma unroll
            for (int ot = 0; ot < 2; ++ot) {
                bf16x8 vh = *(const bf16x8*)(Lb + 8192 + ((kkp*2 + hi) << 10)
                                             + ((ot*32 + l31) << 4));
                bf16x8 vl = *(const bf16x8*)(Lb + 12288 + ((kkp*2 + hi) << 10)
                                             + ((ot*32 + l31) << 4));
                if (ot == 0) { acc0 = mfma32(pa, vh, acc0); acc0 = mfma32(pa, vl, acc0); }
                else         { acc1 = mfma32(pa, vh, acc1); acc1 = mfma32(pa, vl, acc1); }
            }
        }

        asm volatile("" ::: "memory");
        __builtin_amdgcn_s_barrier();
        cur ^= 1;
    }

    // ---- epilogue ----
    lsum += __shfl_xor(lsum, 32);
    float* po = PA + (((size_t)(bh*KS + ks)*Nc + qrow0) << 6);
    #pragma unroll
    for (int r = 0; r < 16; ++r) {
        int row = (r & 3) + 8*(r >> 2) + 4*hi;
        po[((size_t)row << 6) + l31]      = acc0[r];
        po[((size_t)row << 6) + 32 + l31] = acc1[r];
    }
    if (lane < 32)
        PL[(size_t)(bh*KS + ks)*Nc + qrow0 + l31] = lsum;
}

// ---- merge: sum key-splits, divide, mean heads, leaky ----
__global__ void merge_kernel(const float* __restrict__ PA, const float* __restrict__ PL,
                             float* __restrict__ out, int KS)
{
    int gid = blockIdx.x*256 + threadIdx.x;
    int o  = gid & 63;
    int bn = gid >> 6;
    int n  = bn % Nc;
    int b  = bn / Nc;
    float ft = 0.f;
    for (int h = 0; h < Hc; ++h) {
        int bh = b*Hc + h;
        float A = 0.f, L = 0.f;
        for (int ks = 0; ks < KS; ++ks) {
            A += PA[(((size_t)(bh*KS + ks)*Nc + n) << 6) + o];
            L += PL[(size_t)(bh*KS + ks)*Nc + n];
        }
        ft += A / L;
    }
    ft *= 0.25f;
    out[((size_t)bn << 6) + o] = fmaxf(ft, 0.f) + 0.2f*fminf(ft, 0.f);
}

extern "C" void kernel_launch(void* const* d_in, const int* in_sizes, int n_in,
                              void* d_out, int out_size, void* d_ws, size_t ws_size,
                              hipStream_t stream)
{
    const float* x    = (const float*)d_in[0];
    const int*   edge = (const int*)d_in[1];
    const float* Wv   = (const float*)d_in[2];
    const float* bv   = (const float*)d_in[3];
    const float* Wq   = (const float*)d_in[4];
    const float* bq   = (const float*)d_in[5];
    const float* Wk   = (const float*)d_in[6];
    const float* bk   = (const float*)d_in[7];
    float* out = (float*)d_out;

    const size_t PROJ = (size_t)Bc*Hc*Nc*64;          // 1.57M elems per plane
    char* p = (char*)d_ws;
    __bf16* Wbh = (__bf16*)p;   p += 49152*2;
    __bf16* Wbl = (__bf16*)p;   p += 49152*2;
    float*  Bs  = (float*)p;    p += 4096;
    __bf16* Xh  = (__bf16*)p;   p += (size_t)Bc*Nc*64*2;
    __bf16* Xl  = (__bf16*)p;   p += (size_t)Bc*Nc*64*2;
    __bf16* Qh  = (__bf16*)p;   p += PROJ*2;
    __bf16* Ql  = (__bf16*)p;   p += PROJ*2;
    __bf16* Kh  = (__bf16*)p;   p += PROJ*2;
    __bf16* Kl  = (__bf16*)p;   p += PROJ*2;
    __bf16* Vh0 = (__bf16*)p;   p += PROJ*2;
    __bf16* Vl0 = (__bf16*)p;   p += PROJ*2;
    __bf16* KVimg = (__bf16*)p; p += ((size_t)Bc*Hc*96) << 14;
    uint32_t* pmT = (uint32_t*)p; p += (size_t)Bc*NW32*Nc*4;

    int KS = 8;
    for (;;) {
        size_t need = (size_t)(p - (char*)d_ws)
                    + (size_t)Bc*Hc*KS*Nc*64*4 + (size_t)Bc*Hc*KS*Nc*4;
        if (need <= ws_size || KS == 1) break;
        KS >>= 1;
    }
    float* PA = (float*)p;      p += (size_t)Bc*Hc*KS*Nc*64*4;
    float* PL = (float*)p;

    hipLaunchKernelGGL(wb_kernel,     dim3(192),  dim3(256), 0, stream,
                       Wq, Wk, Wv, bq, bk, bv, Wbh, Wbl, Bs);
    hipLaunchKernelGGL(xsplit_kernel, dim3(192),  dim3(256), 0, stream, x, Xh, Xl);
    hipLaunchKernelGGL(qkv_mfma,      dim3(1152), dim3(256), 0, stream,
                       Xh, Xl, Wbh, Wbl, Bs, Qh, Ql, Kh, Kl, Vh0, Vl0);
    hipLaunchKernelGGL(img_kernel,    dim3(Bc*Hc*96), dim3(256), 0, stream,
                       Kh, Kl, Vh0, Vl0, KVimg);
    hipLaunchKernelGGL(pack_kernel,   dim3(Bc*NW32*48/4), dim3(256), 0, stream, edge, pmT);
    hipLaunchKernelGGL(attn_mfma,     dim3(Bc*Hc*KS*24), dim3(256), 0, stream,
                       Qh, Ql, KVimg, pmT, PA, PL, KS, 96/KS);
    hipLaunchKernelGGL(merge_kernel,  dim3((Bc*Nc*64)/256), dim3(256), 0, stream,
                       PA, PL, out, KS);
}

// Round 6
// 102.486 us; speedup vs baseline: 1.0874x; 1.0874x over previous
//
#include <hip/hip_runtime.h>
#include <hip/hip_bf16.h>
#include <cstdint>

#define Bc 2
#define Nc 3072
#define Hc 4
#define NW32 96      // 32-key tiles per row

typedef __bf16 bf16x8 __attribute__((ext_vector_type(8)));
typedef float  f32x16 __attribute__((ext_vector_type(16)));

#define QSCALE 0.18033688f   // 0.125 * log2(e): exp(s/8) == exp2(s*QSCALE)

static __device__ __forceinline__ f32x16 mfma32(bf16x8 a, bf16x8 b, f32x16 c) {
    return __builtin_amdgcn_mfma_f32_32x32x16_bf16(a, b, c, 0, 0, 0);
}
static __device__ __forceinline__ void gload_lds16(const void* g, void* l) {
    __builtin_amdgcn_global_load_lds((const __attribute__((address_space(1))) void*)g,
                                     (__attribute__((address_space(3))) void*)l, 16, 0, 0);
}
static __device__ __forceinline__ uint32_t cvtpk(float lo, float hi) {
    uint32_t w;
    asm("v_cvt_pk_bf16_f32 %0, %1, %2" : "=v"(w) : "v"(lo), "v"(hi));
    return w;
}

// ---- fused prep: W -> bf16 hi/lo [p][h][o][d] (+bias), x -> bf16 hi/lo planes ----
__global__ void prep_kernel(const float* __restrict__ Wq, const float* __restrict__ Wk,
                            const float* __restrict__ Wv,
                            const float* __restrict__ bq, const float* __restrict__ bk,
                            const float* __restrict__ bv, const float* __restrict__ x,
                            __bf16* __restrict__ Wbh, __bf16* __restrict__ Wbl,
                            float* __restrict__ Bs,
                            __bf16* __restrict__ Xh, __bf16* __restrict__ Xl)
{
    if (blockIdx.x < 192) {
        int i = blockIdx.x*256 + threadIdx.x;   // 49152
        int d = i & 63, o = (i >> 6) & 63, h = (i >> 12) & 3, p = i >> 14;
        const float* W = (p == 0) ? Wq : (p == 1) ? Wk : Wv;
        float scale = (p == 0) ? QSCALE : 1.0f;
        float val = W[(h*64 + d)*64 + o] * scale;
        int idx = (((p*Hc + h)*64 + o) << 6) + d;
        __bf16 hi = (__bf16)val;
        Wbh[idx] = hi;
        Wbl[idx] = (__bf16)(val - (float)hi);
        if (i < 3*Hc*64) {
            int pp = i / (Hc*64), rest = i % (Hc*64);
            const float* B = (pp == 0) ? bq : (pp == 1) ? bk : bv;
            Bs[i] = B[rest] * ((pp == 0) ? QSCALE : 1.0f);
        }
    } else {
        int i = (blockIdx.x - 192)*256 + threadIdx.x;   // 49152 x 8 elems
        const float4* xp = (const float4*)(x + (size_t)i*8);
        float4 a = xp[0], c = xp[1];
        float v[8] = {a.x, a.y, a.z, a.w, c.x, c.y, c.z, c.w};
        bf16x8 h, l;
        #pragma unroll
        for (int j = 0; j < 8; ++j) {
            __bf16 hh = (__bf16)v[j];
            h[j] = hh;
            l[j] = (__bf16)(v[j] - (float)hh);
        }
        *(bf16x8*)(Xh + (size_t)i*8) = h;
        *(bf16x8*)(Xl + (size_t)i*8) = l;
    }
}

// ---- QKV projection via MFMA. Q,K -> flat [bh][n][64] hi/lo; V -> KVimg granules ----
__global__ __launch_bounds__(256) void qkv_mfma(
    const __bf16* __restrict__ Xh, const __bf16* __restrict__ Xl,
    const __bf16* __restrict__ Wbh, const __bf16* __restrict__ Wbl,
    const float* __restrict__ Bs,
    __bf16* __restrict__ Qh, __bf16* __restrict__ Ql,
    __bf16* __restrict__ Kh, __bf16* __restrict__ Kl,
    __bf16* __restrict__ KVimg)
{
    const int lane = threadIdx.x & 63, w = threadIdx.x >> 6;
    const int l31 = lane & 31, hi = lane >> 5;
    int t = blockIdx.x;                 // 1152 blocks
    int nt = t % 48; t /= 48;
    int b  = t & 1;  t >>= 1;
    int p  = t % 3;
    int h  = t / 3;
    const int r0 = (w >> 1)*32, c0 = (w & 1)*32, n0 = nt*64;

    bf16x8 xh[4], xl[4], wh[4], wl[4];
    #pragma unroll
    for (int kk = 0; kk < 4; ++kk) {
        size_t xoff = (((size_t)(b*Nc + n0 + r0 + l31)) << 6) + kk*16 + hi*8;
        xh[kk] = *(const bf16x8*)(Xh + xoff);
        xl[kk] = *(const bf16x8*)(Xl + xoff);
        size_t woff = (((size_t)((p*Hc + h)*64 + c0 + l31)) << 6) + kk*16 + hi*8;
        wh[kk] = *(const bf16x8*)(Wbh + woff);
        wl[kk] = *(const bf16x8*)(Wbl + woff);
    }
    float bias = Bs[(p*Hc + h)*64 + c0 + l31];
    f32x16 acc;
    #pragma unroll
    for (int i = 0; i < 16; ++i) acc[i] = bias;
    #pragma unroll
    for (int kk = 0; kk < 4; ++kk) {
        acc = mfma32(xh[kk], wh[kk], acc);
        acc = mfma32(xl[kk], wh[kk], acc);
        acc = mfma32(xh[kk], wl[kk], acc);
    }
    const int bh = b*Hc + h;
    if (p < 2) {
        __bf16* dh = (p == 0) ? Qh : Kh;
        __bf16* dl = (p == 0) ? Ql : Kl;
        #pragma unroll
        for (int r = 0; r < 16; ++r) {
            int row = (r & 3) + 8*(r >> 2) + 4*hi;
            size_t idx = (((size_t)bh*Nc + n0 + r0 + row) << 6) + c0 + l31;
            float val = acc[r];
            __bf16 hh = (__bf16)val;
            dh[idx] = hh;
            dl[idx] = (__bf16)(val - (float)hh);
        }
    } else {
        // V: write image granules directly (granule (kb,o) = V[kb*8..+7][o])
        const int t_img = (n0 + r0) >> 5;
        char* img = (char*)KVimg + (((size_t)bh*96 + t_img) << 14);
        #pragma unroll
        for (int grp = 0; grp < 2; ++grp) {       // acc regs grp*8 .. grp*8+7
            uint32_t wH[4], wL[4];
            #pragma unroll
            for (int j = 0; j < 4; ++j) {
                float a0 = acc[grp*8 + 2*j], a1 = acc[grp*8 + 2*j + 1];
                uint32_t ww = cvtpk(a0, a1);
                wH[j] = ww;
                float l0 = a0 - __uint_as_float(ww << 16);
                float l1 = a1 - __uint_as_float(ww & 0xffff0000u);
                wL[j] = cvtpk(l0, l1);
            }
            asm("v_permlane32_swap_b32 %0, %1" : "+v"(wH[0]), "+v"(wH[2]));
            asm("v_permlane32_swap_b32 %0, %1" : "+v"(wH[1]), "+v"(wH[3]));
            asm("v_permlane32_swap_b32 %0, %1" : "+v"(wL[0]), "+v"(wL[2]));
            asm("v_permlane32_swap_b32 %0, %1" : "+v"(wL[1]), "+v"(wL[3]));
            const int kb = grp*2 + hi;
            const int o  = c0 + l31;
            uint4 gh = {wH[0], wH[1], wH[2], wH[3]};
            uint4 gl = {wL[0], wL[1], wL[2], wL[3]};
            *(uint4*)(img + 8192 + ((kb*64 + o) << 4)) = gh;
            *(uint4*)(img + 8192 + 4096 + ((kb*64 + o) << 4)) = gl;
        }
    }
}

// ---- K image: granule (dc,key) = K[key][dc*8..+7] (hi at 0, lo at +4096) ----
__global__ void imgk_kernel(const __bf16* __restrict__ Kh, const __bf16* __restrict__ Kl,
                            __bf16* __restrict__ KVimg)
{
    const int tid = threadIdx.x;
    const int t = blockIdx.x % 96, bh = blockIdx.x / 96;
    char* img = (char*)KVimg + (((size_t)bh*96 + t) << 14);
    int dc = tid & 7, key = tid >> 3;
    size_t src = (((size_t)bh*Nc + t*32 + key) << 6) + dc*8;
    *(uint4*)(img + (dc*32 + key)*16)        = *(const uint4*)(Kh + src);
    *(uint4*)(img + 4096 + (dc*32 + key)*16) = *(const uint4*)(Kl + src);
}

// ---- pack adjacency transposed: pmT[b][w][n], bit j = edge[b][n][32w+j] ----
__global__ void pack_kernel(const int* __restrict__ edge, uint32_t* __restrict__ pmT)
{
    int gw = blockIdx.x*4 + (threadIdx.x >> 6);
    int lane = threadIdx.x & 63;
    int ng = gw % 48; gw /= 48;
    int w  = gw % NW32; gw /= NW32;
    int b  = gw;
    int n = ng*64 + lane;
    const uint4* ep = (const uint4*)(edge + ((size_t)b*Nc + n)*Nc + w*32);
    uint32_t word = 0;
    #pragma unroll
    for (int i = 0; i < 8; ++i) {
        uint4 e = ep[i];
        word |= (e.x ? 1u : 0u) << (4*i);
        word |= (e.y ? 1u : 0u) << (4*i + 1);
        word |= (e.z ? 1u : 0u) << (4*i + 2);
        word |= (e.w ? 1u : 0u) << (4*i + 3);
    }
    pmT[((size_t)b*NW32 + w)*Nc + n] = word;
}

// ---- flash attention: mask-prefetch + counted-vmcnt pipeline, denom via ones-MFMA ----
__global__ __launch_bounds__(256, 4) void attn_mfma(
    const __bf16* __restrict__ Qh, const __bf16* __restrict__ Ql,
    const __bf16* __restrict__ KVimg, const uint32_t* __restrict__ pmT,
    float* __restrict__ PA, float* __restrict__ PL, int KS, int tps)
{
    __shared__ __align__(16) char ldsKV[2][16384];
    const int lane = threadIdx.x & 63, w = threadIdx.x >> 6;
    const int l31 = lane & 31, hi = lane >> 5;
    int gb = blockIdx.x;
    const int bh = gb & 7; gb >>= 3;        // XCD swizzle: one bh per XCD
    const int qt = gb % 24;
    const int ks = gb / 24;
    const int b = bh >> 2;
    const int qrow0 = qt*128 + w*32;
    const int t0 = ks*tps;

    // mask for tile t0: load BEFORE stage so vmcnt(4) covers it (in-order retire)
    const uint32_t* pmp = pmT + ((size_t)b*NW32 + t0)*Nc + qrow0 + l31;
    uint32_t mw_cur = *pmp;
    __builtin_amdgcn_sched_barrier(0);
    const char* gsrc = (const char*)KVimg + (((size_t)bh*96 + t0) << 14)
                     + w*4096 + lane*16;
    #pragma unroll
    for (int g = 0; g < 4; ++g)
        gload_lds16(gsrc + g*1024, &ldsKV[0][w*4096 + g*1024]);

    // Q B-frags (col = q-row = l31, k = d), pre-scaled by QSCALE
    bf16x8 qh[4], ql[4];
    #pragma unroll
    for (int kk = 0; kk < 4; ++kk) {
        size_t qoff = (((size_t)bh*Nc + qrow0 + l31) << 6) + kk*16 + hi*8;
        qh[kk] = *(const bf16x8*)(Qh + qoff);
        ql[kk] = *(const bf16x8*)(Ql + qoff);
    }
    bf16x8 ones;
    #pragma unroll
    for (int j = 0; j < 8; ++j) ones[j] = (__bf16)1.0f;

    f32x16 acc0, acc1, acc2;
    #pragma unroll
    for (int i = 0; i < 16; ++i) { acc0[i] = 0.f; acc1[i] = 0.f; acc2[i] = 0.f; }

    int cur = 0;
    #pragma unroll 1
    for (int it = 0; it < tps; ++it) {
        const int adv = (it + 1 < tps) ? 1 : 0;
        // prefetch NEXT mask first, then next stage -> vmcnt(4) retires mask+cur stage
        uint32_t mw_next = pmp[(size_t)(adv * Nc)];
        pmp += adv * Nc;
        __builtin_amdgcn_sched_barrier(0);
        const char* gnext = gsrc + ((size_t)adv << 14);
        {
            char* ldst = &ldsKV[cur ^ 1][w*4096];
            #pragma unroll
            for (int g = 0; g < 4; ++g)
                gload_lds16(gnext + g*1024, ldst + g*1024);
        }
        gsrc = gnext;
        asm volatile("s_waitcnt vmcnt(4)" ::: "memory");
        __builtin_amdgcn_s_barrier();
        const char* Lb = &ldsKV[cur][0];

        // ---- QK^T: 12 MFMA (split-bf16, 3 terms) ----
        f32x16 sc;
        #pragma unroll
        for (int i = 0; i < 16; ++i) sc[i] = 0.f;
        __builtin_amdgcn_s_setprio(1);
        #pragma unroll
        for (int kk = 0; kk < 4; ++kk) {
            bf16x8 ka = *(const bf16x8*)(Lb + ((kk*2 + hi) << 9) + (l31 << 4));
            bf16x8 la = *(const bf16x8*)(Lb + 4096 + ((kk*2 + hi) << 9) + (l31 << 4));
            sc = mfma32(ka, qh[kk], sc);
            sc = mfma32(la, qh[kk], sc);
            sc = mfma32(ka, ql[kk], sc);
        }
        __builtin_amdgcn_s_setprio(0);

        // ---- in-register softmax: leaky+exp2, pack, mask packed word ----
        uint32_t mwh = mw_cur >> (hi*4);
        uint32_t W8[8];
        #pragma unroll
        for (int i = 0; i < 8; ++i) {
            const int bp0 = (2*i & 3) + 8*(2*i >> 2);   // bp1 = bp0+1
            float s0 = sc[2*i], s1 = sc[2*i + 1];
            float a0 = fmaxf(s0, 0.2f*s0);
            float a1 = fmaxf(s1, 0.2f*s1);
            float e0, e1;
            asm("v_exp_f32 %0, %1" : "=v"(e0) : "v"(a0));
            asm("v_exp_f32 %0, %1" : "=v"(e1) : "v"(a1));
            uint32_t pk = cvtpk(e0, e1);
            uint32_t m0 = (uint32_t)(((int)(mwh << (31 - bp0))) >> 31);
            uint32_t m1 = (uint32_t)(((int)(mwh << (30 - bp0))) >> 31);
            W8[i] = pk & ((m0 & 0x0000ffffu) | (m1 & 0xffff0000u));
        }
        mw_cur = mw_next;

        // ---- permlane assembly of PV A-frags ----
        uint32_t a0 = W8[0], a2 = W8[2], a1 = W8[1], a3 = W8[3];
        uint32_t b0 = W8[4], b2 = W8[6], b1 = W8[5], b3 = W8[7];
        asm("v_permlane32_swap_b32 %0, %1" : "+v"(a0), "+v"(a2));
        asm("v_permlane32_swap_b32 %0, %1" : "+v"(a1), "+v"(a3));
        asm("v_permlane32_swap_b32 %0, %1" : "+v"(b0), "+v"(b2));
        asm("v_permlane32_swap_b32 %0, %1" : "+v"(b1), "+v"(b3));
        union { uint32_t u[4]; bf16x8 v; } pa0, pa1;
        pa0.u[0] = a0; pa0.u[1] = a1; pa0.u[2] = a2; pa0.u[3] = a3;
        pa1.u[0] = b0; pa1.u[1] = b1; pa1.u[2] = b2; pa1.u[3] = b3;

        // ---- PV (8 MFMA) + denominator (2 MFMA, B = ones) ----
        __builtin_amdgcn_s_setprio(1);
        acc2 = mfma32(pa0.v, ones, acc2);
        acc2 = mfma32(pa1.v, ones, acc2);
        #pragma unroll
        for (int kkp = 0; kkp < 2; ++kkp) {
            bf16x8 pa = kkp ? pa1.v : pa0.v;
            #pragma unroll
            for (int ot = 0; ot < 2; ++ot) {
                bf16x8 vh = *(const bf16x8*)(Lb + 8192 + ((kkp*2 + hi) << 10)
                                             + ((ot*32 + l31) << 4));
                bf16x8 vl = *(const bf16x8*)(Lb + 12288 + ((kkp*2 + hi) << 10)
                                             + ((ot*32 + l31) << 4));
                if (ot == 0) { acc0 = mfma32(pa, vh, acc0); acc0 = mfma32(pa, vl, acc0); }
                else         { acc1 = mfma32(pa, vh, acc1); acc1 = mfma32(pa, vl, acc1); }
            }
        }
        __builtin_amdgcn_s_setprio(0);

        asm volatile("" ::: "memory");
        __builtin_amdgcn_s_barrier();
        cur ^= 1;
    }

    // ---- epilogue: PA[bh][ks][n][o], PL[bh][ks][n] (rowsum in acc2, all cols equal) ----
    float* po = PA + (((size_t)(bh*KS + ks)*Nc + qrow0) << 6);
    #pragma unroll
    for (int r = 0; r < 16; ++r) {
        int row = (r & 3) + 8*(r >> 2) + 4*hi;
        po[((size_t)row << 6) + l31]      = acc0[r];
        po[((size_t)row << 6) + 32 + l31] = acc1[r];
    }
    if (l31 == 0) {
        float* pl = PL + (size_t)(bh*KS + ks)*Nc + qrow0;
        #pragma unroll
        for (int r = 0; r < 16; ++r)
            pl[(r & 3) + 8*(r >> 2) + 4*hi] = acc2[r];
    }
}

// ---- merge: sum key-splits, divide, mean heads, leaky ----
__global__ void merge_kernel(const float* __restrict__ PA, const float* __restrict__ PL,
                             float* __restrict__ out, int KS)
{
    int gid = blockIdx.x*256 + threadIdx.x;
    int o  = gid & 63;
    int bn = gid >> 6;
    int n  = bn % Nc;
    int b  = bn / Nc;
    float ft = 0.f;
    for (int h = 0; h < Hc; ++h) {
        int bh = b*Hc + h;
        float A = 0.f, L = 0.f;
        for (int ks = 0; ks < KS; ++ks) {
            A += PA[(((size_t)(bh*KS + ks)*Nc + n) << 6) + o];
            L += PL[(size_t)(bh*KS + ks)*Nc + n];
        }
        ft += A / L;
    }
    ft *= 0.25f;
    out[((size_t)bn << 6) + o] = fmaxf(ft, 0.f) + 0.2f*fminf(ft, 0.f);
}

extern "C" void kernel_launch(void* const* d_in, const int* in_sizes, int n_in,
                              void* d_out, int out_size, void* d_ws, size_t ws_size,
                              hipStream_t stream)
{
    const float* x    = (const float*)d_in[0];
    const int*   edge = (const int*)d_in[1];
    const float* Wv   = (const float*)d_in[2];
    const float* bv   = (const float*)d_in[3];
    const float* Wq   = (const float*)d_in[4];
    const float* bq   = (const float*)d_in[5];
    const float* Wk   = (const float*)d_in[6];
    const float* bk   = (const float*)d_in[7];
    float* out = (float*)d_out;

    const size_t PROJ = (size_t)Bc*Hc*Nc*64;
    char* p = (char*)d_ws;
    __bf16* Wbh = (__bf16*)p;   p += 49152*2;
    __bf16* Wbl = (__bf16*)p;   p += 49152*2;
    float*  Bs  = (float*)p;    p += 4096;
    __bf16* Xh  = (__bf16*)p;   p += (size_t)Bc*Nc*64*2;
    __bf16* Xl  = (__bf16*)p;   p += (size_t)Bc*Nc*64*2;
    __bf16* Qh  = (__bf16*)p;   p += PROJ*2;
    __bf16* Ql  = (__bf16*)p;   p += PROJ*2;
    __bf16* Kh  = (__bf16*)p;   p += PROJ*2;
    __bf16* Kl  = (__bf16*)p;   p += PROJ*2;
    __bf16* KVimg = (__bf16*)p; p += ((size_t)Bc*Hc*96) << 14;
    uint32_t* pmT = (uint32_t*)p; p += (size_t)Bc*NW32*Nc*4;

    int KS = 4;   // grid 768 = exactly 3 blocks/CU, zero tail
    for (;;) {
        size_t need = (size_t)(p - (char*)d_ws)
                    + (size_t)Bc*Hc*KS*Nc*64*4 + (size_t)Bc*Hc*KS*Nc*4;
        if (need <= ws_size || KS == 1) break;
        KS >>= 1;
    }
    float* PA = (float*)p;      p += (size_t)Bc*Hc*KS*Nc*64*4;
    float* PL = (float*)p;

    hipLaunchKernelGGL(prep_kernel, dim3(384),  dim3(256), 0, stream,
                       Wq, Wk, Wv, bq, bk, bv, x, Wbh, Wbl, Bs, Xh, Xl);
    hipLaunchKernelGGL(qkv_mfma,    dim3(1152), dim3(256), 0, stream,
                       Xh, Xl, Wbh, Wbl, Bs, Qh, Ql, Kh, Kl, KVimg);
    hipLaunchKernelGGL(imgk_kernel, dim3(Bc*Hc*96), dim3(256), 0, stream, Kh, Kl, KVimg);
    hipLaunchKernelGGL(pack_kernel, dim3(Bc*NW32*48/4), dim3(256), 0, stream, edge, pmT);
    hipLaunchKernelGGL(attn_mfma,   dim3(Bc*Hc*KS*24), dim3(256), 0, stream,
                       Qh, Ql, KVimg, pmT, PA, PL, KS, 96/KS);
    hipLaunchKernelGGL(merge_kernel, dim3((Bc*Nc*64)/256), dim3(256), 0, stream,
                       PA, PL, out, KS);
}